// Round 1
// baseline (168.935 us; speedup 1.0000x reference)
//
#include <hip/hip_runtime.h>
#include <hip/hip_bf16.h>

// Problem constants
constexpr int   D      = 512;
constexpr int   NP     = 128;
constexpr int   BSZ    = 32;          // 8192 / (2*128)
constexpr float ALPHA  = 1.0f;
constexpr float EPS    = 1e-9f;
constexpr float INV_CNT = 1.0f / (32.0f * 128.0f * 128.0f);  // 1/524288

// ws layout (bytes)
constexpr size_t NORM_OFF = 0;                       // 8192*512*4  = 16777216
constexpr size_t GRAM_OFF = 16777216;                // 32*3*128*128*4 = 6291456
constexpr size_t PART_OFF = GRAM_OFF + 6291456;      // 2048*4

// ---------------------------------------------------------------------------
// K1: row-normalize. One wave per row (512 floats). 2048 blocks x 256.
__global__ __launch_bounds__(256) void k_normalize(const float* __restrict__ in,
                                                   float* __restrict__ out) {
    const int wid  = threadIdx.x >> 6;
    const int lane = threadIdx.x & 63;
    const int r    = blockIdx.x * 4 + wid;
    const float4* src = (const float4*)(in + (size_t)r * D);
    float4 x0 = src[lane];
    float4 x1 = src[lane + 64];
    float ss = x0.x*x0.x + x0.y*x0.y + x0.z*x0.z + x0.w*x0.w
             + x1.x*x1.x + x1.y*x1.y + x1.z*x1.z + x1.w*x1.w;
    #pragma unroll
    for (int o = 32; o > 0; o >>= 1) ss += __shfl_xor(ss, o, 64);
    const float inv = rsqrtf(ss);
    x0.x *= inv; x0.y *= inv; x0.z *= inv; x0.w *= inv;
    x1.x *= inv; x1.y *= inv; x1.z *= inv; x1.w *= inv;
    float4* dst = (float4*)(out + (size_t)r * D);
    dst[lane]      = x0;
    dst[lane + 64] = x1;
}

// ---------------------------------------------------------------------------
// K2: Gram matrices. G[b][m][i][j], m: 0=t.t^T, 1=c.c^T, 2=t.c^T.
// grid = 32*3*8 = 768 blocks; block computes 16 rows x 128 cols.
// Thread: j = tid&127, rows i0..i0+7 (i0 = rc*16 + (tid>>7)*8).
__global__ __launch_bounds__(256) void k_gram(const float* __restrict__ nrm,
                                              float* __restrict__ gram) {
    const int bx = blockIdx.x;
    const int rc = bx & 7;
    const int m  = (bx >> 3) % 3;
    const int b  = bx / 24;

    const float* tbase = nrm + (size_t)b * 256 * D;
    const float* cbase = tbase + (size_t)NP * D;
    const float* A = (m == 1) ? cbase : tbase;
    const float* B = (m == 0) ? tbase : cbase;

    const int j  = threadIdx.x & 127;
    const int i0 = rc * 16 + (threadIdx.x >> 7) * 8;

    const float4* brow = (const float4*)(B + (size_t)j * D);
    const float4* ar0 = (const float4*)(A + (size_t)(i0 + 0) * D);
    const float4* ar1 = (const float4*)(A + (size_t)(i0 + 1) * D);
    const float4* ar2 = (const float4*)(A + (size_t)(i0 + 2) * D);
    const float4* ar3 = (const float4*)(A + (size_t)(i0 + 3) * D);
    const float4* ar4 = (const float4*)(A + (size_t)(i0 + 4) * D);
    const float4* ar5 = (const float4*)(A + (size_t)(i0 + 5) * D);
    const float4* ar6 = (const float4*)(A + (size_t)(i0 + 6) * D);
    const float4* ar7 = (const float4*)(A + (size_t)(i0 + 7) * D);

    float acc[8] = {0.f, 0.f, 0.f, 0.f, 0.f, 0.f, 0.f, 0.f};

    #pragma unroll 4
    for (int k = 0; k < D / 4; k++) {
        const float4 bv = brow[k];
        float4 av;
        av = ar0[k]; acc[0] += av.x*bv.x + av.y*bv.y + av.z*bv.z + av.w*bv.w;
        av = ar1[k]; acc[1] += av.x*bv.x + av.y*bv.y + av.z*bv.z + av.w*bv.w;
        av = ar2[k]; acc[2] += av.x*bv.x + av.y*bv.y + av.z*bv.z + av.w*bv.w;
        av = ar3[k]; acc[3] += av.x*bv.x + av.y*bv.y + av.z*bv.z + av.w*bv.w;
        av = ar4[k]; acc[4] += av.x*bv.x + av.y*bv.y + av.z*bv.z + av.w*bv.w;
        av = ar5[k]; acc[5] += av.x*bv.x + av.y*bv.y + av.z*bv.z + av.w*bv.w;
        av = ar6[k]; acc[6] += av.x*bv.x + av.y*bv.y + av.z*bv.z + av.w*bv.w;
        av = ar7[k]; acc[7] += av.x*bv.x + av.y*bv.y + av.z*bv.z + av.w*bv.w;
    }

    float* g = gram + ((size_t)(b * 3 + m) * NP + i0) * NP + j;
    #pragma unroll
    for (int r = 0; r < 8; r++) g[(size_t)r * NP] = acc[r];
}

// ---------------------------------------------------------------------------
// K3: loss. One wave per (b, side, i): 8192 waves -> 2048 blocks x 256.
// Lane handles j = lane and j = lane+64.
__global__ __launch_bounds__(256) void k_loss(const float* __restrict__ gram,
                                              float* __restrict__ part) {
    __shared__ float bsh[4][128];
    __shared__ float red[4];

    const int wid  = threadIdx.x >> 6;
    const int lane = threadIdx.x & 63;
    const int w    = blockIdx.x * 4 + wid;
    const int i    = w & 127;
    const int side = (w >> 7) & 1;
    const int b    = w >> 8;

    const float* gb  = gram + (size_t)b * 3 * NP * NP;
    const float* pd  = gb + (size_t)side * NP * NP + (size_t)i * NP;  // Gtt or Gcc, row i
    const float* gtc = gb + (size_t)2 * NP * NP;

    // pn_dist row: side0 -> Gtc row i; side1 -> Gtc column i (== Gct row i)
    float bv0, bv1;
    if (side == 0) {
        bv0 = gtc[(size_t)i * NP + lane];
        bv1 = gtc[(size_t)i * NP + lane + 64];
    } else {
        bv0 = gtc[(size_t)lane * NP + i];
        bv1 = gtc[(size_t)(lane + 64) * NP + i];
    }
    bsh[wid][lane]      = 2.0f - 2.0f * bv0;   // pn_dist[i][lane]
    bsh[wid][lane + 64] = 2.0f - 2.0f * bv1;   // pn_dist[i][lane+64]
    __builtin_amdgcn_s_waitcnt(0);             // lgkmcnt(0) for own-wave LDS writes
    // (wave-private LDS row: no cross-wave sync needed)

    const float a0 = ALPHA + 2.0f - 2.0f * pd[lane];
    const float a1 = ALPHA + 2.0f - 2.0f * pd[lane + 64];

    float sum0 = 0.f, sum1 = 0.f, cnt0 = 0.f, cnt1 = 0.f;
    #pragma unroll 8
    for (int k = 0; k < NP; k++) {
        const float bk = bsh[wid][k];
        const float v0 = a0 - bk;
        const float v1 = a1 - bk;
        sum0 += fmaxf(v0, 0.f);
        sum1 += fmaxf(v1, 0.f);
        cnt0 += (v0 > 0.f) ? 1.f : 0.f;
        cnt1 += (v1 > 0.f) ? 1.f : 0.f;
    }

    float c = sum0 / (cnt0 + EPS) + sum1 / (cnt1 + EPS);
    #pragma unroll
    for (int o = 32; o > 0; o >>= 1) c += __shfl_xor(c, o, 64);

    if (lane == 0) red[wid] = c;
    __syncthreads();
    if (threadIdx.x == 0) part[blockIdx.x] = red[0] + red[1] + red[2] + red[3];
}

// ---------------------------------------------------------------------------
// K4: final reduction of 2048 partials -> scalar loss.
__global__ __launch_bounds__(256) void k_reduce(const float* __restrict__ part,
                                                float* __restrict__ out) {
    __shared__ float red[4];
    const int wid  = threadIdx.x >> 6;
    const int lane = threadIdx.x & 63;
    float s = 0.f;
    for (int idx = threadIdx.x; idx < 2048; idx += 256) s += part[idx];
    #pragma unroll
    for (int o = 32; o > 0; o >>= 1) s += __shfl_xor(s, o, 64);
    if (lane == 0) red[wid] = s;
    __syncthreads();
    if (threadIdx.x == 0) out[0] = (red[0] + red[1] + red[2] + red[3]) * INV_CNT;
}

// ---------------------------------------------------------------------------
extern "C" void kernel_launch(void* const* d_in, const int* in_sizes, int n_in,
                              void* d_out, int out_size, void* d_ws, size_t ws_size,
                              hipStream_t stream) {
    const float* latent = (const float*)d_in[0];
    float* out = (float*)d_out;
    char* wsb = (char*)d_ws;
    float* nrm  = (float*)(wsb + NORM_OFF);
    float* gram = (float*)(wsb + GRAM_OFF);
    float* part = (float*)(wsb + PART_OFF);

    hipLaunchKernelGGL(k_normalize, dim3(2048), dim3(256), 0, stream, latent, nrm);
    hipLaunchKernelGGL(k_gram,      dim3(768),  dim3(256), 0, stream, nrm, gram);
    hipLaunchKernelGGL(k_loss,      dim3(2048), dim3(256), 0, stream, gram, part);
    hipLaunchKernelGGL(k_reduce,    dim3(1),    dim3(256), 0, stream, part, out);
}

// Round 2
// 50.663 us; speedup vs baseline: 3.3345x; 3.3345x over previous
//
#include <hip/hip_runtime.h>
#include <hip/hip_bf16.h>

// Problem constants
constexpr int   D      = 512;
constexpr int   NP     = 128;
constexpr float ALPHA  = 1.0f;
constexpr float EPS    = 1e-9f;
constexpr float INV_CNT = 1.0f / (32.0f * 128.0f * 128.0f);  // 1/524288

// ws layout (bytes)
constexpr size_t NORM_OFF = 0;                        // 8192*512*2 = 8388608 (bf16)
constexpr size_t GRAM_OFF = 8388608;                  // 32*3*128*128*4 = 6291456
constexpr size_t PART_OFF = GRAM_OFF + 6291456;       // 2048*4

typedef short bf16x8 __attribute__((ext_vector_type(8)));
typedef float f32x4  __attribute__((ext_vector_type(4)));

// round-to-nearest-even f32 -> bf16 bits
__device__ __forceinline__ short f2bf(float f) {
    unsigned u = __builtin_bit_cast(unsigned, f);
    unsigned r = (u + 0x7FFFu + ((u >> 16) & 1u)) >> 16;
    return (short)r;
}

// ---------------------------------------------------------------------------
// K1: row-normalize fp32 -> bf16. One wave per row. 2048 blocks x 256.
__global__ __launch_bounds__(256) void k_normalize(const float* __restrict__ in,
                                                   short* __restrict__ out) {
    const int wid  = threadIdx.x >> 6;
    const int lane = threadIdx.x & 63;
    const int r    = blockIdx.x * 4 + wid;
    const float4* src = (const float4*)(in + (size_t)r * D);
    // lane handles elements [8*lane, 8*lane+8)
    float4 x0 = src[2 * lane];
    float4 x1 = src[2 * lane + 1];
    float ss = x0.x*x0.x + x0.y*x0.y + x0.z*x0.z + x0.w*x0.w
             + x1.x*x1.x + x1.y*x1.y + x1.z*x1.z + x1.w*x1.w;
    #pragma unroll
    for (int o = 32; o > 0; o >>= 1) ss += __shfl_xor(ss, o, 64);
    const float inv = rsqrtf(ss);
    bf16x8 v;
    v[0] = f2bf(x0.x * inv); v[1] = f2bf(x0.y * inv);
    v[2] = f2bf(x0.z * inv); v[3] = f2bf(x0.w * inv);
    v[4] = f2bf(x1.x * inv); v[5] = f2bf(x1.y * inv);
    v[6] = f2bf(x1.z * inv); v[7] = f2bf(x1.w * inv);
    ((bf16x8*)(out + (size_t)r * D))[lane] = v;
}

// ---------------------------------------------------------------------------
// K2: Gram via MFMA. G[b][m][i][j] = A_i . B_j, m: 0=tt, 1=cc, 2=tc.
// grid = 32*3*2 = 192 blocks; block computes 64 rows x 128 cols.
// 4 waves; wave (wr,wc) computes rows [wr*32,+32) x cols [wc*64,+64).
__global__ __launch_bounds__(256) void k_gram_mfma(const short* __restrict__ nrm,
                                                   float* __restrict__ gram) {
    const int bx   = blockIdx.x;
    const int half = bx & 1;
    const int m    = (bx >> 1) % 3;
    const int b    = bx / 6;

    const short* tbase = nrm + (size_t)b * 256 * D;
    const short* cbase = tbase + (size_t)NP * D;
    const short* Asrc = (m == 1) ? cbase : tbase;
    const short* Bsrc = (m == 0) ? tbase : cbase;

    const int wave = threadIdx.x >> 6;
    const int lane = threadIdx.x & 63;
    const int wr   = wave >> 1;             // 0..1
    const int wc   = wave & 1;              // 0..1
    const int row0 = half * 64 + wr * 32;   // A rows [row0, row0+32)
    const int col0 = wc * 64;               // B rows [col0, col0+64)

    const int fr = lane & 15;   // fragment row index
    const int kg = lane >> 4;   // k-group: k offset 8*kg within a 32-chunk

    const short* Abase = Asrc + (size_t)(row0 + fr) * D + 8 * kg;
    const short* Bbase = Bsrc + (size_t)(col0 + fr) * D + 8 * kg;

    f32x4 acc[2][4];
    #pragma unroll
    for (int i = 0; i < 2; i++)
        #pragma unroll
        for (int j = 0; j < 4; j++)
            acc[i][j] = (f32x4){0.f, 0.f, 0.f, 0.f};

    #pragma unroll 4
    for (int ks = 0; ks < 16; ks++) {
        const int k0 = ks * 32;
        bf16x8 a0 = *(const bf16x8*)(Abase + k0);
        bf16x8 a1 = *(const bf16x8*)(Abase + 16 * D + k0);
        bf16x8 b0 = *(const bf16x8*)(Bbase + k0);
        bf16x8 b1 = *(const bf16x8*)(Bbase + 16 * D + k0);
        bf16x8 b2 = *(const bf16x8*)(Bbase + 32 * D + k0);
        bf16x8 b3 = *(const bf16x8*)(Bbase + 48 * D + k0);
        acc[0][0] = __builtin_amdgcn_mfma_f32_16x16x32_bf16(a0, b0, acc[0][0], 0, 0, 0);
        acc[0][1] = __builtin_amdgcn_mfma_f32_16x16x32_bf16(a0, b1, acc[0][1], 0, 0, 0);
        acc[0][2] = __builtin_amdgcn_mfma_f32_16x16x32_bf16(a0, b2, acc[0][2], 0, 0, 0);
        acc[0][3] = __builtin_amdgcn_mfma_f32_16x16x32_bf16(a0, b3, acc[0][3], 0, 0, 0);
        acc[1][0] = __builtin_amdgcn_mfma_f32_16x16x32_bf16(a1, b0, acc[1][0], 0, 0, 0);
        acc[1][1] = __builtin_amdgcn_mfma_f32_16x16x32_bf16(a1, b1, acc[1][1], 0, 0, 0);
        acc[1][2] = __builtin_amdgcn_mfma_f32_16x16x32_bf16(a1, b2, acc[1][2], 0, 0, 0);
        acc[1][3] = __builtin_amdgcn_mfma_f32_16x16x32_bf16(a1, b3, acc[1][3], 0, 0, 0);
    }

    // C/D layout (m89-verified): lane l, reg r holds D[(l>>4)*4 + r][l&15]
    float* g = gram + (size_t)(b * 3 + m) * NP * NP;
    #pragma unroll
    for (int i = 0; i < 2; i++) {
        #pragma unroll
        for (int j = 0; j < 4; j++) {
            const int rbase = row0 + i * 16 + 4 * kg;
            const int c     = col0 + j * 16 + fr;
            #pragma unroll
            for (int r = 0; r < 4; r++)
                g[(size_t)(rbase + r) * NP + c] = acc[i][j][r];
        }
    }
}

// ---------------------------------------------------------------------------
// K3: loss. One wave per (b, side, i): 8192 waves -> 2048 blocks x 256.
// Lane handles j = lane and j = lane+64.
__global__ __launch_bounds__(256) void k_loss(const float* __restrict__ gram,
                                              float* __restrict__ part) {
    __shared__ float bsh[4][128];
    __shared__ float red[4];

    const int wid  = threadIdx.x >> 6;
    const int lane = threadIdx.x & 63;
    const int w    = blockIdx.x * 4 + wid;
    const int i    = w & 127;
    const int side = (w >> 7) & 1;
    const int b    = w >> 8;

    const float* gb  = gram + (size_t)b * 3 * NP * NP;
    const float* pd  = gb + (size_t)side * NP * NP + (size_t)i * NP;  // Gtt or Gcc, row i
    const float* gtc = gb + (size_t)2 * NP * NP;

    // pn_dist row: side0 -> Gtc row i; side1 -> Gtc column i (== Gct row i)
    float bv0, bv1;
    if (side == 0) {
        bv0 = gtc[(size_t)i * NP + lane];
        bv1 = gtc[(size_t)i * NP + lane + 64];
    } else {
        bv0 = gtc[(size_t)lane * NP + i];
        bv1 = gtc[(size_t)(lane + 64) * NP + i];
    }
    bsh[wid][lane]      = 2.0f - 2.0f * bv0;   // pn_dist[i][lane]
    bsh[wid][lane + 64] = 2.0f - 2.0f * bv1;   // pn_dist[i][lane+64]
    __builtin_amdgcn_s_waitcnt(0);             // own-wave LDS writes visible
    // (wave-private LDS row: no cross-wave sync needed)

    const float a0 = ALPHA + 2.0f - 2.0f * pd[lane];
    const float a1 = ALPHA + 2.0f - 2.0f * pd[lane + 64];

    float sum0 = 0.f, sum1 = 0.f, cnt0 = 0.f, cnt1 = 0.f;
    #pragma unroll 8
    for (int k = 0; k < NP; k++) {
        const float bk = bsh[wid][k];
        const float v0 = a0 - bk;
        const float v1 = a1 - bk;
        sum0 += fmaxf(v0, 0.f);
        sum1 += fmaxf(v1, 0.f);
        cnt0 += (v0 > 0.f) ? 1.f : 0.f;
        cnt1 += (v1 > 0.f) ? 1.f : 0.f;
    }

    float c = sum0 / (cnt0 + EPS) + sum1 / (cnt1 + EPS);
    #pragma unroll
    for (int o = 32; o > 0; o >>= 1) c += __shfl_xor(c, o, 64);

    if (lane == 0) red[wid] = c;
    __syncthreads();
    if (threadIdx.x == 0) part[blockIdx.x] = red[0] + red[1] + red[2] + red[3];
}

// ---------------------------------------------------------------------------
// K4: final reduction of 2048 partials -> scalar loss.
__global__ __launch_bounds__(256) void k_reduce(const float* __restrict__ part,
                                                float* __restrict__ out) {
    __shared__ float red[4];
    const int wid  = threadIdx.x >> 6;
    const int lane = threadIdx.x & 63;
    float s = 0.f;
    for (int idx = threadIdx.x; idx < 2048; idx += 256) s += part[idx];
    #pragma unroll
    for (int o = 32; o > 0; o >>= 1) s += __shfl_xor(s, o, 64);
    if (lane == 0) red[wid] = s;
    __syncthreads();
    if (threadIdx.x == 0) out[0] = (red[0] + red[1] + red[2] + red[3]) * INV_CNT;
}

// ---------------------------------------------------------------------------
extern "C" void kernel_launch(void* const* d_in, const int* in_sizes, int n_in,
                              void* d_out, int out_size, void* d_ws, size_t ws_size,
                              hipStream_t stream) {
    const float* latent = (const float*)d_in[0];
    float* out = (float*)d_out;
    char* wsb = (char*)d_ws;
    short* nrm  = (short*)(wsb + NORM_OFF);
    float* gram = (float*)(wsb + GRAM_OFF);
    float* part = (float*)(wsb + PART_OFF);

    hipLaunchKernelGGL(k_normalize, dim3(2048), dim3(256), 0, stream, latent, nrm);
    hipLaunchKernelGGL(k_gram_mfma, dim3(192),  dim3(256), 0, stream, nrm, gram);
    hipLaunchKernelGGL(k_loss,      dim3(2048), dim3(256), 0, stream, gram, part);
    hipLaunchKernelGGL(k_reduce,    dim3(1),    dim3(256), 0, stream, part, out);
}

// Round 3
// 47.005 us; speedup vs baseline: 3.5940x; 1.0778x over previous
//
#include <hip/hip_runtime.h>
#include <hip/hip_bf16.h>

// Problem constants
constexpr int   D      = 512;
constexpr int   NP     = 128;
constexpr float ALPHA  = 1.0f;
constexpr float EPS    = 1e-9f;
constexpr float INV_CNT = 1.0f / (32.0f * 128.0f * 128.0f);  // 1/524288

// ws layout (bytes)
constexpr size_t NORM_OFF = 0;           // 8192*512*2 = 8388608 (bf16)
constexpr size_t PART_OFF = 8388608;     // 256*4

typedef short bf16x8 __attribute__((ext_vector_type(8)));
typedef float f32x4  __attribute__((ext_vector_type(4)));

// round-to-nearest-even f32 -> bf16 bits
__device__ __forceinline__ short f2bf(float f) {
    unsigned u = __builtin_bit_cast(unsigned, f);
    unsigned r = (u + 0x7FFFu + ((u >> 16) & 1u)) >> 16;
    return (short)r;
}

// ---------------------------------------------------------------------------
// K1: row-normalize fp32 -> bf16. One wave per row. 2048 blocks x 256.
__global__ __launch_bounds__(256) void k_normalize(const float* __restrict__ in,
                                                   short* __restrict__ out) {
    const int wid  = threadIdx.x >> 6;
    const int lane = threadIdx.x & 63;
    const int r    = blockIdx.x * 4 + wid;
    const float4* src = (const float4*)(in + (size_t)r * D);
    float4 x0 = src[2 * lane];
    float4 x1 = src[2 * lane + 1];
    float ss = x0.x*x0.x + x0.y*x0.y + x0.z*x0.z + x0.w*x0.w
             + x1.x*x1.x + x1.y*x1.y + x1.z*x1.z + x1.w*x1.w;
    #pragma unroll
    for (int o = 32; o > 0; o >>= 1) ss += __shfl_xor(ss, o, 64);
    const float inv = rsqrtf(ss);
    bf16x8 v;
    v[0] = f2bf(x0.x * inv); v[1] = f2bf(x0.y * inv);
    v[2] = f2bf(x0.z * inv); v[3] = f2bf(x0.w * inv);
    v[4] = f2bf(x1.x * inv); v[5] = f2bf(x1.y * inv);
    v[6] = f2bf(x1.z * inv); v[7] = f2bf(x1.w * inv);
    ((bf16x8*)(out + (size_t)r * D))[lane] = v;
}

// ---------------------------------------------------------------------------
// K2: fused gram+loss. grid = 32 batches x 8 chunks = 256 blocks, 512 threads.
// Per block: A = [t[chunk16]; c[chunk16]] (32 rows), B = [t; c] (256 rows).
// P = A . B^T (32x256, MFMA) -> LDS. Panels:
//   P[0:16,  0:128] = Gtt[chunk,:]  (pd, side0)
//   P[0:16,128:256] = Gtc[chunk,:]  (pn, side0)
//   P[16:32,128:256] = Gcc[chunk,:] (pd, side1)
//   P[16:32, 0:128] = Gct[chunk,:]  (pn, side1)  <- row access, no col gather
// Then loss over 32 (side,i) rows, 4 per wave, lane owns j=lane & j=lane+64.
constexpr int PSTR = 260;   // padded f32 row stride: +4 keeps C-write conflicts 2-way (free)

__global__ __launch_bounds__(512) void k_fused(const short* __restrict__ nrm,
                                               float* __restrict__ part) {
    __shared__ float P[32 * PSTR];
    __shared__ float red[8];

    const int bx    = blockIdx.x;
    const int b     = bx >> 3;
    const int chunk = bx & 7;
    const int wave  = threadIdx.x >> 6;
    const int lane  = threadIdx.x & 63;
    const int fr    = lane & 15;
    const int kg    = lane >> 4;

    const short* base = nrm + (size_t)b * 256 * D;
    // A fragments: rows chunk*16+fr (t) and 128+chunk*16+fr (c), k-offset 8*kg
    const short* gA0 = base + (size_t)(chunk * 16 + fr) * D + 8 * kg;
    const short* gA1 = gA0 + (size_t)NP * D;
    // B fragments: wave's 32-col group
    const int cg = wave * 32;
    const short* gB0 = base + (size_t)(cg + fr) * D + 8 * kg;
    const short* gB1 = gB0 + (size_t)16 * D;

    f32x4 acc00 = {0.f,0.f,0.f,0.f}, acc01 = {0.f,0.f,0.f,0.f};
    f32x4 acc10 = {0.f,0.f,0.f,0.f}, acc11 = {0.f,0.f,0.f,0.f};

    #pragma unroll 4
    for (int ks = 0; ks < 16; ks++) {
        const int off = ks * 32;
        bf16x8 a0 = *(const bf16x8*)(gA0 + off);
        bf16x8 a1 = *(const bf16x8*)(gA1 + off);
        bf16x8 b0 = *(const bf16x8*)(gB0 + off);
        bf16x8 b1 = *(const bf16x8*)(gB1 + off);
        acc00 = __builtin_amdgcn_mfma_f32_16x16x32_bf16(a0, b0, acc00, 0, 0, 0);
        acc01 = __builtin_amdgcn_mfma_f32_16x16x32_bf16(a0, b1, acc01, 0, 0, 0);
        acc10 = __builtin_amdgcn_mfma_f32_16x16x32_bf16(a1, b0, acc10, 0, 0, 0);
        acc11 = __builtin_amdgcn_mfma_f32_16x16x32_bf16(a1, b1, acc11, 0, 0, 0);
    }

    // C/D layout (m89-verified): lane l, reg q -> row (l>>4)*4+q, col l&15
    {
        const int rw = kg * 4;
        const int cw = cg + fr;
        #pragma unroll
        for (int q = 0; q < 4; q++) P[(rw + q) * PSTR + cw]           = acc00[q];
        #pragma unroll
        for (int q = 0; q < 4; q++) P[(rw + q) * PSTR + cw + 16]     = acc01[q];
        #pragma unroll
        for (int q = 0; q < 4; q++) P[(16 + rw + q) * PSTR + cw]     = acc10[q];
        #pragma unroll
        for (int q = 0; q < 4; q++) P[(16 + rw + q) * PSTR + cw + 16] = acc11[q];
    }
    __syncthreads();

    // Loss phase: v(j,k) = ALPHA - 2*pd[j] + 2*pn[k]
    float wacc = 0.f;
    #pragma unroll
    for (int rr = 0; rr < 4; rr++) {
        const int r      = wave * 4 + rr;
        const int pd_off = (r < 16) ? 0 : 128;
        const int pn_off = 128 - pd_off;
        const float* prow = &P[r * PSTR];

        const float a0 = ALPHA - 2.f * prow[pd_off + lane];
        const float a1 = ALPHA - 2.f * prow[pd_off + lane + 64];

        float sum0 = 0.f, sum1 = 0.f;
        unsigned cnt0 = 0, cnt1 = 0;
        #pragma unroll 8
        for (int kk = 0; kk < 64; kk++) {
            const float2 pk = *(const float2*)&prow[pn_off + 2 * kk];
            float v;
            v = fmaf(2.f, pk.x, a0); sum0 += fmaxf(v, 0.f); cnt0 += (v > 0.f);
            v = fmaf(2.f, pk.x, a1); sum1 += fmaxf(v, 0.f); cnt1 += (v > 0.f);
            v = fmaf(2.f, pk.y, a0); sum0 += fmaxf(v, 0.f); cnt0 += (v > 0.f);
            v = fmaf(2.f, pk.y, a1); sum1 += fmaxf(v, 0.f); cnt1 += (v > 0.f);
        }
        wacc += sum0 / ((float)cnt0 + EPS) + sum1 / ((float)cnt1 + EPS);
    }

    #pragma unroll
    for (int o = 32; o > 0; o >>= 1) wacc += __shfl_xor(wacc, o, 64);
    if (lane == 0) red[wave] = wacc;
    __syncthreads();
    if (threadIdx.x == 0) {
        float s = 0.f;
        #pragma unroll
        for (int i = 0; i < 8; i++) s += red[i];
        part[bx] = s;
    }
}

// ---------------------------------------------------------------------------
// K3: final reduction of 256 partials -> scalar loss.
__global__ __launch_bounds__(256) void k_reduce(const float* __restrict__ part,
                                                float* __restrict__ out) {
    __shared__ float red[4];
    const int wid  = threadIdx.x >> 6;
    const int lane = threadIdx.x & 63;
    float s = part[threadIdx.x];
    #pragma unroll
    for (int o = 32; o > 0; o >>= 1) s += __shfl_xor(s, o, 64);
    if (lane == 0) red[wid] = s;
    __syncthreads();
    if (threadIdx.x == 0) out[0] = (red[0] + red[1] + red[2] + red[3]) * INV_CNT;
}

// ---------------------------------------------------------------------------
extern "C" void kernel_launch(void* const* d_in, const int* in_sizes, int n_in,
                              void* d_out, int out_size, void* d_ws, size_t ws_size,
                              hipStream_t stream) {
    const float* latent = (const float*)d_in[0];
    float* out = (float*)d_out;
    char* wsb = (char*)d_ws;
    short* nrm  = (short*)(wsb + NORM_OFF);
    float* part = (float*)(wsb + PART_OFF);

    hipLaunchKernelGGL(k_normalize, dim3(2048), dim3(256), 0, stream, latent, nrm);
    hipLaunchKernelGGL(k_fused,     dim3(256),  dim3(512), 0, stream, nrm, part);
    hipLaunchKernelGGL(k_reduce,    dim3(1),    dim3(256), 0, stream, part, out);
}

// Round 4
// 41.983 us; speedup vs baseline: 4.0239x; 1.1196x over previous
//
#include <hip/hip_runtime.h>
#include <hip/hip_bf16.h>

// Problem constants
constexpr int   D      = 512;
constexpr int   NP     = 128;
constexpr float ALPHA  = 1.0f;
constexpr float EPS    = 1e-9f;
constexpr float INV_CNT = 1.0f / (32.0f * 128.0f * 128.0f);  // 1/524288

// ws layout (bytes)
constexpr size_t NORM_OFF = 0;           // 8192*512*2 = 8388608 (bf16)
constexpr size_t PART_OFF = 8388608;     // 256*4

typedef short bf16x8 __attribute__((ext_vector_type(8)));
typedef float f32x4  __attribute__((ext_vector_type(4)));

// round-to-nearest-even f32 -> bf16 bits
__device__ __forceinline__ short f2bf(float f) {
    unsigned u = __builtin_bit_cast(unsigned, f);
    unsigned r = (u + 0x7FFFu + ((u >> 16) & 1u)) >> 16;
    return (short)r;
}

// ---------------------------------------------------------------------------
// K1: row-normalize fp32 -> bf16. One wave per row. 2048 blocks x 256.
__global__ __launch_bounds__(256) void k_normalize(const float* __restrict__ in,
                                                   short* __restrict__ out) {
    const int wid  = threadIdx.x >> 6;
    const int lane = threadIdx.x & 63;
    const int r    = blockIdx.x * 4 + wid;
    const float4* src = (const float4*)(in + (size_t)r * D);
    float4 x0 = src[2 * lane];
    float4 x1 = src[2 * lane + 1];
    float ss = x0.x*x0.x + x0.y*x0.y + x0.z*x0.z + x0.w*x0.w
             + x1.x*x1.x + x1.y*x1.y + x1.z*x1.z + x1.w*x1.w;
    #pragma unroll
    for (int o = 32; o > 0; o >>= 1) ss += __shfl_xor(ss, o, 64);
    const float inv = rsqrtf(ss);
    bf16x8 v;
    v[0] = f2bf(x0.x * inv); v[1] = f2bf(x0.y * inv);
    v[2] = f2bf(x0.z * inv); v[3] = f2bf(x0.w * inv);
    v[4] = f2bf(x1.x * inv); v[5] = f2bf(x1.y * inv);
    v[6] = f2bf(x1.z * inv); v[7] = f2bf(x1.w * inv);
    ((bf16x8*)(out + (size_t)r * D))[lane] = v;
}

// ---------------------------------------------------------------------------
// K2: fused gram+loss. grid = 32 batches x 8 chunks = 256 blocks, 512 threads.
// MFMA phase: P = [t16;c16] . [t;c]^T (32x256) -> LDS (verified round 2/3).
// Loss phase (NEW): per row, sort pn (128) ascending via in-wave bitonic
// (2 elems/lane), prefix-scan, then per-j 8-step binary-search rank:
//   num(j) = cntGT*(ALPHA-2g_j) + 2*sufsum,  den = cntGT + EPS
constexpr int PSTR = 260;   // padded f32 row stride

__global__ __launch_bounds__(512) void k_fused(const short* __restrict__ nrm,
                                               float* __restrict__ part) {
    __shared__ float P[32 * PSTR];
    __shared__ float red[8];

    const int bx    = blockIdx.x;
    const int b     = bx >> 3;
    const int chunk = bx & 7;
    const int wave  = threadIdx.x >> 6;
    const int lane  = threadIdx.x & 63;
    const int fr    = lane & 15;
    const int kg    = lane >> 4;

    const short* base = nrm + (size_t)b * 256 * D;
    const short* gA0 = base + (size_t)(chunk * 16 + fr) * D + 8 * kg;
    const short* gA1 = gA0 + (size_t)NP * D;
    const int cg = wave * 32;
    const short* gB0 = base + (size_t)(cg + fr) * D + 8 * kg;
    const short* gB1 = gB0 + (size_t)16 * D;

    f32x4 acc00 = {0.f,0.f,0.f,0.f}, acc01 = {0.f,0.f,0.f,0.f};
    f32x4 acc10 = {0.f,0.f,0.f,0.f}, acc11 = {0.f,0.f,0.f,0.f};

    #pragma unroll 8
    for (int ks = 0; ks < 16; ks++) {
        const int off = ks * 32;
        bf16x8 a0 = *(const bf16x8*)(gA0 + off);
        bf16x8 a1 = *(const bf16x8*)(gA1 + off);
        bf16x8 b0 = *(const bf16x8*)(gB0 + off);
        bf16x8 b1 = *(const bf16x8*)(gB1 + off);
        acc00 = __builtin_amdgcn_mfma_f32_16x16x32_bf16(a0, b0, acc00, 0, 0, 0);
        acc01 = __builtin_amdgcn_mfma_f32_16x16x32_bf16(a0, b1, acc01, 0, 0, 0);
        acc10 = __builtin_amdgcn_mfma_f32_16x16x32_bf16(a1, b0, acc10, 0, 0, 0);
        acc11 = __builtin_amdgcn_mfma_f32_16x16x32_bf16(a1, b1, acc11, 0, 0, 0);
    }

    // C/D layout (m89-verified): lane l, reg q -> row (l>>4)*4+q, col l&15
    {
        const int rw = kg * 4;
        const int cw = cg + fr;
        #pragma unroll
        for (int q = 0; q < 4; q++) P[(rw + q) * PSTR + cw]            = acc00[q];
        #pragma unroll
        for (int q = 0; q < 4; q++) P[(rw + q) * PSTR + cw + 16]      = acc01[q];
        #pragma unroll
        for (int q = 0; q < 4; q++) P[(16 + rw + q) * PSTR + cw]      = acc10[q];
        #pragma unroll
        for (int q = 0; q < 4; q++) P[(16 + rw + q) * PSTR + cw + 16] = acc11[q];
    }
    __syncthreads();

    // ---- Loss phase: 4 rows per wave, wave-private. ----
    float wacc = 0.f;
    #pragma unroll
    for (int rr = 0; rr < 4; rr++) {
        const int r      = wave * 4 + rr;
        const int pd_off = (r < 16) ? 0 : 128;
        const int pn_off = 128 - pd_off;
        float* prow = &P[r * PSTR];

        // read pd thresholds and pn values into registers BEFORE overwrite
        const float g0 = prow[pd_off + lane];
        const float g1 = prow[pd_off + lane + 64];
        float v0 = prow[pn_off + lane];         // element index lane
        float v1 = prow[pn_off + lane + 64];    // element index lane+64

        // --- bitonic sort ascending; index i: v0<->lane, v1<->lane+64 ---
        #pragma unroll
        for (int kk = 2; kk <= 128; kk <<= 1) {
            if (kk == 128) {                    // j=64 step: cross-reg, same lane
                const float lo = fminf(v0, v1);
                const float hi = fmaxf(v0, v1);
                v0 = lo; v1 = hi;
            }
            #pragma unroll
            for (int j = (kk == 128 ? 32 : (kk >> 1)); j >= 1; j >>= 1) {
                const float p0 = __shfl_xor(v0, j, 64);
                const float p1 = __shfl_xor(v1, j, 64);
                const bool up0 = (lane & kk) == 0;
                const bool up1 = ((lane + 64) & kk) == 0;
                const bool lower = (lane & j) == 0;
                v0 = (up0 == lower) ? fminf(v0, p0) : fmaxf(v0, p0);
                v1 = (up1 == lower) ? fminf(v1, p1) : fmaxf(v1, p1);
            }
        }

        // --- inclusive prefix scans of the two halves ---
        float inc0 = v0, inc1 = v1;
        #pragma unroll
        for (int o = 1; o < 64; o <<= 1) {
            const float t0 = __shfl_up(inc0, o, 64);
            const float t1 = __shfl_up(inc1, o, 64);
            if (lane >= o) { inc0 += t0; inc1 += t1; }
        }
        const float tot0  = __shfl(inc0, 63, 64);
        const float total = tot0 + __shfl(inc1, 63, 64);

        // --- write sorted s[0:128] and exclusive prefix pre[0:129] ---
        prow[lane]            = v0;
        prow[64 + lane]       = v1;
        prow[130 + 1 + lane]  = inc0;         // pre[lane+1]
        prow[130 + 65 + lane] = tot0 + inc1;  // pre[65+lane]; lane63 -> pre[128]=total
        if (lane == 0) prow[130] = 0.f;

        // --- per-j: rank via guarded binary search, closed-form num/den ---
        #pragma unroll
        for (int h = 0; h < 2; h++) {
            const float g   = h ? g1 : g0;
            const float tau = g - 0.5f * ALPHA;   // v>0  <=>  h_k > tau
            const float a   = ALPHA - 2.f * g;
            int pos = 0;                           // rank = #{s_k <= tau}
            #pragma unroll
            for (int st = 128; st > 0; st >>= 1) {
                const int nidx = pos + st;
                const float sv = prow[nidx - 1];   // max idx 191 < 260, safe
                pos = ((nidx <= 128) && (sv <= tau)) ? nidx : pos;
            }
            const float cnt = (float)(128 - pos);
            const float pre = prow[130 + pos];
            const float num = cnt * a + 2.f * (total - pre);
            wacc += num / (cnt + EPS);
        }
    }

    #pragma unroll
    for (int o = 32; o > 0; o >>= 1) wacc += __shfl_xor(wacc, o, 64);
    if (lane == 0) red[wave] = wacc;
    __syncthreads();
    if (threadIdx.x == 0) {
        float s = 0.f;
        #pragma unroll
        for (int i = 0; i < 8; i++) s += red[i];
        part[bx] = s;
    }
}

// ---------------------------------------------------------------------------
// K3: final reduction of 256 partials -> scalar loss.
__global__ __launch_bounds__(256) void k_reduce(const float* __restrict__ part,
                                                float* __restrict__ out) {
    __shared__ float red[4];
    const int wid  = threadIdx.x >> 6;
    const int lane = threadIdx.x & 63;
    float s = part[threadIdx.x];
    #pragma unroll
    for (int o = 32; o > 0; o >>= 1) s += __shfl_xor(s, o, 64);
    if (lane == 0) red[wid] = s;
    __syncthreads();
    if (threadIdx.x == 0) out[0] = (red[0] + red[1] + red[2] + red[3]) * INV_CNT;
}

// ---------------------------------------------------------------------------
extern "C" void kernel_launch(void* const* d_in, const int* in_sizes, int n_in,
                              void* d_out, int out_size, void* d_ws, size_t ws_size,
                              hipStream_t stream) {
    const float* latent = (const float*)d_in[0];
    float* out = (float*)d_out;
    char* wsb = (char*)d_ws;
    short* nrm  = (short*)(wsb + NORM_OFF);
    float* part = (float*)(wsb + PART_OFF);

    hipLaunchKernelGGL(k_normalize, dim3(2048), dim3(256), 0, stream, latent, nrm);
    hipLaunchKernelGGL(k_fused,     dim3(256),  dim3(512), 0, stream, nrm, part);
    hipLaunchKernelGGL(k_reduce,    dim3(1),    dim3(256), 0, stream, part, out);
}

// Round 5
// 41.750 us; speedup vs baseline: 4.0463x; 1.0056x over previous
//
#include <hip/hip_runtime.h>
#include <hip/hip_bf16.h>

// Problem constants
constexpr int   D      = 512;
constexpr int   NP     = 128;
constexpr float ALPHA  = 1.0f;
constexpr float EPS    = 1e-9f;
constexpr float INV_CNT = 1.0f / (32.0f * 128.0f * 128.0f);  // 1/524288

// ws layout (bytes)
constexpr size_t NORM_OFF = 0;           // 8192*512*2 = 8388608 (bf16)
constexpr size_t PART_OFF = 8388608;     // 256*4

typedef short bf16x8 __attribute__((ext_vector_type(8)));
typedef float f32x4  __attribute__((ext_vector_type(4)));

// round-to-nearest-even f32 -> bf16 bits
__device__ __forceinline__ short f2bf(float f) {
    unsigned u = __builtin_bit_cast(unsigned, f);
    unsigned r = (u + 0x7FFFu + ((u >> 16) & 1u)) >> 16;
    return (short)r;
}

// ---------------------------------------------------------------------------
// K1: row-normalize fp32 -> bf16. One wave per row. 2048 blocks x 256.
__global__ __launch_bounds__(256) void k_normalize(const float* __restrict__ in,
                                                   short* __restrict__ out) {
    const int wid  = threadIdx.x >> 6;
    const int lane = threadIdx.x & 63;
    const int r    = blockIdx.x * 4 + wid;
    const float4* src = (const float4*)(in + (size_t)r * D);
    float4 x0 = src[2 * lane];
    float4 x1 = src[2 * lane + 1];
    float ss = x0.x*x0.x + x0.y*x0.y + x0.z*x0.z + x0.w*x0.w
             + x1.x*x1.x + x1.y*x1.y + x1.z*x1.z + x1.w*x1.w;
    #pragma unroll
    for (int o = 32; o > 0; o >>= 1) ss += __shfl_xor(ss, o, 64);
    const float inv = rsqrtf(ss);
    bf16x8 v;
    v[0] = f2bf(x0.x * inv); v[1] = f2bf(x0.y * inv);
    v[2] = f2bf(x0.z * inv); v[3] = f2bf(x0.w * inv);
    v[4] = f2bf(x1.x * inv); v[5] = f2bf(x1.y * inv);
    v[6] = f2bf(x1.z * inv); v[7] = f2bf(x1.w * inv);
    ((bf16x8*)(out + (size_t)r * D))[lane] = v;
}

// ---------------------------------------------------------------------------
// K2: fused gram+loss. grid = 256 blocks x 512 threads.
// XCD swizzle: physical block p (round-robin p%8 -> XCD) maps to
//   xcd = p&7, slot = p>>3, b = xcd*4 + (slot&3), chunk = slot>>2
// so each XCD hosts 4 whole batches (1 MB working set, L2-resident; the 8
// chunk-blocks of a batch share its 264 KB B-panel through that XCD's L2).
// MFMA phase: P = [t16;c16].[t;c]^T (32x256) -> LDS, distance-2 reg prefetch.
// Loss phase: per-row bitonic sort + prefix + binary-search closed form
// (verified rounds 3-4, absmax 0).
constexpr int PSTR = 260;   // padded f32 row stride

__global__ __launch_bounds__(512) void k_fused(const short* __restrict__ nrm,
                                               float* __restrict__ part) {
    __shared__ float P[32 * PSTR];
    __shared__ float red[8];

    const int p     = blockIdx.x;
    const int slot  = p >> 3;
    const int b     = (p & 7) * 4 + (slot & 3);
    const int chunk = slot >> 2;
    const int wave  = threadIdx.x >> 6;
    const int lane  = threadIdx.x & 63;
    const int fr    = lane & 15;
    const int kg    = lane >> 4;

    const short* base = nrm + (size_t)b * 256 * D;
    const short* gA0 = base + (size_t)(chunk * 16 + fr) * D + 8 * kg;
    const short* gA1 = gA0 + (size_t)NP * D;
    const int cg = wave * 32;
    const short* gB0 = base + (size_t)(cg + fr) * D + 8 * kg;
    const short* gB1 = gB0 + (size_t)16 * D;

    f32x4 acc00 = {0.f,0.f,0.f,0.f}, acc01 = {0.f,0.f,0.f,0.f};
    f32x4 acc10 = {0.f,0.f,0.f,0.f}, acc11 = {0.f,0.f,0.f,0.f};

    // distance-2 register prefetch; 3 rotating buffers, full unroll => static idx
    bf16x8 bA0[3], bA1[3], bB0[3], bB1[3];
    #pragma unroll
    for (int i = 0; i < 2; i++) {
        const int off = i * 32;
        bA0[i] = *(const bf16x8*)(gA0 + off);
        bA1[i] = *(const bf16x8*)(gA1 + off);
        bB0[i] = *(const bf16x8*)(gB0 + off);
        bB1[i] = *(const bf16x8*)(gB1 + off);
    }
    #pragma unroll
    for (int ks = 0; ks < 16; ks++) {
        const int cur = ks % 3;
        const int pf  = (ks + 2) % 3;
        if (ks + 2 < 16) {
            const int off = (ks + 2) * 32;
            bA0[pf] = *(const bf16x8*)(gA0 + off);
            bA1[pf] = *(const bf16x8*)(gA1 + off);
            bB0[pf] = *(const bf16x8*)(gB0 + off);
            bB1[pf] = *(const bf16x8*)(gB1 + off);
        }
        acc00 = __builtin_amdgcn_mfma_f32_16x16x32_bf16(bA0[cur], bB0[cur], acc00, 0, 0, 0);
        acc01 = __builtin_amdgcn_mfma_f32_16x16x32_bf16(bA0[cur], bB1[cur], acc01, 0, 0, 0);
        acc10 = __builtin_amdgcn_mfma_f32_16x16x32_bf16(bA1[cur], bB0[cur], acc10, 0, 0, 0);
        acc11 = __builtin_amdgcn_mfma_f32_16x16x32_bf16(bA1[cur], bB1[cur], acc11, 0, 0, 0);
    }

    // C/D layout (m89-verified): lane l, reg q -> row (l>>4)*4+q, col l&15
    {
        const int rw = kg * 4;
        const int cw = cg + fr;
        #pragma unroll
        for (int q = 0; q < 4; q++) P[(rw + q) * PSTR + cw]            = acc00[q];
        #pragma unroll
        for (int q = 0; q < 4; q++) P[(rw + q) * PSTR + cw + 16]      = acc01[q];
        #pragma unroll
        for (int q = 0; q < 4; q++) P[(16 + rw + q) * PSTR + cw]      = acc10[q];
        #pragma unroll
        for (int q = 0; q < 4; q++) P[(16 + rw + q) * PSTR + cw + 16] = acc11[q];
    }
    __syncthreads();

    // ---- Loss phase: 4 rows per wave, wave-private. ----
    float wacc = 0.f;
    #pragma unroll
    for (int rr = 0; rr < 4; rr++) {
        const int r      = wave * 4 + rr;
        const int pd_off = (r < 16) ? 0 : 128;
        const int pn_off = 128 - pd_off;
        float* prow = &P[r * PSTR];

        // read pd thresholds and pn values into registers BEFORE overwrite
        const float g0 = prow[pd_off + lane];
        const float g1 = prow[pd_off + lane + 64];
        float v0 = prow[pn_off + lane];
        float v1 = prow[pn_off + lane + 64];

        // --- bitonic sort ascending (2 elems/lane) ---
        #pragma unroll
        for (int kk = 2; kk <= 128; kk <<= 1) {
            if (kk == 128) {
                const float lo = fminf(v0, v1);
                const float hi = fmaxf(v0, v1);
                v0 = lo; v1 = hi;
            }
            #pragma unroll
            for (int j = (kk == 128 ? 32 : (kk >> 1)); j >= 1; j >>= 1) {
                const float p0 = __shfl_xor(v0, j, 64);
                const float p1 = __shfl_xor(v1, j, 64);
                const bool up0 = (lane & kk) == 0;
                const bool up1 = ((lane + 64) & kk) == 0;
                const bool lower = (lane & j) == 0;
                v0 = (up0 == lower) ? fminf(v0, p0) : fmaxf(v0, p0);
                v1 = (up1 == lower) ? fminf(v1, p1) : fmaxf(v1, p1);
            }
        }

        // --- inclusive prefix scans of the two halves ---
        float inc0 = v0, inc1 = v1;
        #pragma unroll
        for (int o = 1; o < 64; o <<= 1) {
            const float t0 = __shfl_up(inc0, o, 64);
            const float t1 = __shfl_up(inc1, o, 64);
            if (lane >= o) { inc0 += t0; inc1 += t1; }
        }
        const float tot0  = __shfl(inc0, 63, 64);
        const float total = tot0 + __shfl(inc1, 63, 64);

        // --- write sorted s[0:128] and exclusive prefix pre[0:129] ---
        prow[lane]            = v0;
        prow[64 + lane]       = v1;
        prow[130 + 1 + lane]  = inc0;         // pre[lane+1]
        prow[130 + 65 + lane] = tot0 + inc1;  // pre[65+lane]
        if (lane == 0) prow[130] = 0.f;

        // --- per-j: rank via guarded binary search, closed-form num/den ---
        #pragma unroll
        for (int h = 0; h < 2; h++) {
            const float g   = h ? g1 : g0;
            const float tau = g - 0.5f * ALPHA;   // v>0  <=>  h_k > tau
            const float a   = ALPHA - 2.f * g;
            int pos = 0;                           // rank = #{s_k <= tau}
            #pragma unroll
            for (int st = 128; st > 0; st >>= 1) {
                const int nidx = pos + st;
                const float sv = prow[nidx - 1];
                pos = ((nidx <= 128) && (sv <= tau)) ? nidx : pos;
            }
            const float cnt = (float)(128 - pos);
            const float pre = prow[130 + pos];
            const float num = cnt * a + 2.f * (total - pre);
            wacc += num / (cnt + EPS);
        }
    }

    #pragma unroll
    for (int o = 32; o > 0; o >>= 1) wacc += __shfl_xor(wacc, o, 64);
    if (lane == 0) red[wave] = wacc;
    __syncthreads();
    if (threadIdx.x == 0) {
        float s = 0.f;
        #pragma unroll
        for (int i = 0; i < 8; i++) s += red[i];
        part[p] = s;
    }
}

// ---------------------------------------------------------------------------
// K3: final reduction of 256 partials -> scalar loss.
__global__ __launch_bounds__(256) void k_reduce(const float* __restrict__ part,
                                                float* __restrict__ out) {
    __shared__ float red[4];
    const int wid  = threadIdx.x >> 6;
    const int lane = threadIdx.x & 63;
    float s = part[threadIdx.x];
    #pragma unroll
    for (int o = 32; o > 0; o >>= 1) s += __shfl_xor(s, o, 64);
    if (lane == 0) red[wid] = s;
    __syncthreads();
    if (threadIdx.x == 0) out[0] = (red[0] + red[1] + red[2] + red[3]) * INV_CNT;
}

// ---------------------------------------------------------------------------
extern "C" void kernel_launch(void* const* d_in, const int* in_sizes, int n_in,
                              void* d_out, int out_size, void* d_ws, size_t ws_size,
                              hipStream_t stream) {
    const float* latent = (const float*)d_in[0];
    float* out = (float*)d_out;
    char* wsb = (char*)d_ws;
    short* nrm  = (short*)(wsb + NORM_OFF);
    float* part = (float*)(wsb + PART_OFF);

    hipLaunchKernelGGL(k_normalize, dim3(2048), dim3(256), 0, stream, latent, nrm);
    hipLaunchKernelGGL(k_fused,     dim3(256),  dim3(512), 0, stream, nrm, part);
    hipLaunchKernelGGL(k_reduce,    dim3(1),    dim3(256), 0, stream, part, out);
}

// Round 6
// 37.470 us; speedup vs baseline: 4.5085x; 1.1142x over previous
//
#include <hip/hip_runtime.h>
#include <hip/hip_bf16.h>

// Problem constants
constexpr int   D      = 512;
constexpr int   NP     = 128;
constexpr float ALPHA  = 1.0f;
constexpr float EPS    = 1e-9f;
constexpr float INV_CNT = 1.0f / (32.0f * 128.0f * 128.0f);  // 1/524288

// ws layout (bytes)
constexpr size_t NORM_OFF = 0;           // 8192*512*2 = 8388608 (bf16)
constexpr size_t PART_OFF = 8388608;     // 256*4

typedef short bf16x8 __attribute__((ext_vector_type(8)));
typedef float f32x4  __attribute__((ext_vector_type(4)));

// round-to-nearest-even f32 -> bf16 bits
__device__ __forceinline__ short f2bf(float f) {
    unsigned u = __builtin_bit_cast(unsigned, f);
    unsigned r = (u + 0x7FFFu + ((u >> 16) & 1u)) >> 16;
    return (short)r;
}

// async global->LDS, 16B per lane; dest = uniform base + lane*16 (HW rule)
typedef __attribute__((address_space(3))) char lds_char;
typedef const __attribute__((address_space(1))) char g_char;
__device__ __forceinline__ void glds16(const void* g, void* l) {
    __builtin_amdgcn_global_load_lds((g_char*)g, (lds_char*)l, 16, 0, 0);
}

// ---------------------------------------------------------------------------
// K1: row-normalize fp32 -> bf16. One wave per row. 2048 blocks x 256.
__global__ __launch_bounds__(256) void k_normalize(const float* __restrict__ in,
                                                   short* __restrict__ out) {
    const int wid  = threadIdx.x >> 6;
    const int lane = threadIdx.x & 63;
    const int r    = blockIdx.x * 4 + wid;
    const float4* src = (const float4*)(in + (size_t)r * D);
    float4 x0 = src[2 * lane];
    float4 x1 = src[2 * lane + 1];
    float ss = x0.x*x0.x + x0.y*x0.y + x0.z*x0.z + x0.w*x0.w
             + x1.x*x1.x + x1.y*x1.y + x1.z*x1.z + x1.w*x1.w;
    #pragma unroll
    for (int o = 32; o > 0; o >>= 1) ss += __shfl_xor(ss, o, 64);
    const float inv = rsqrtf(ss);
    bf16x8 v;
    v[0] = f2bf(x0.x * inv); v[1] = f2bf(x0.y * inv);
    v[2] = f2bf(x0.z * inv); v[3] = f2bf(x0.w * inv);
    v[4] = f2bf(x1.x * inv); v[5] = f2bf(x1.y * inv);
    v[6] = f2bf(x1.z * inv); v[7] = f2bf(x1.w * inv);
    ((bf16x8*)(out + (size_t)r * D))[lane] = v;
}

// ---------------------------------------------------------------------------
// K2: fused gram+loss. grid = 256 blocks x 512 threads (XCD-swizzled).
// MFMA phase (NEW structure):
//   A (32 rows x 512 bf16) -> 128 VGPRs per lane (32 one-time loads, L1-shared
//   across the 8 waves since all waves use identical A fragments).
//   B: wave-private glds staging. BK=32 slices; slice = 32 rows x 64B per
//   wave (2 glds issues). Triple buffer (3 x 16 KB), distance-2 prefetch,
//   hand-counted s_waitcnt vmcnt (only B glds live in the loop's VMEM queue).
//   Chunk-XOR swizzle p = kg ^ (row&3) applied on the global SOURCE (linear
//   LDS dest, per m104/m173) and on the ds_read position -> <=4-way banks.
// Then P(32x256) -> LDS overlay, loss via sort+prefix+binsearch (verified).
constexpr int PSTR = 260;                 // padded f32 row stride for P
constexpr int BBUF = 16384;               // one B slice buffer (256 rows x 64B)

__global__ __launch_bounds__(512, 2) void k_fused(const short* __restrict__ nrm,
                                                  float* __restrict__ part) {
    __shared__ __align__(16) char smem[49184];   // B 3x16K; P overlays [0,33280); red @49152

    const int p     = blockIdx.x;
    const int slot  = p >> 3;
    const int b     = (p & 7) * 4 + (slot & 3);   // XCD-bijective: 4 batches/XCD
    const int chunk = slot >> 2;
    const int w     = threadIdx.x >> 6;
    const int lane  = threadIdx.x & 63;
    const int fr    = lane & 15;
    const int kg    = lane >> 4;

    const short* base = nrm + (size_t)b * 256 * D;
    const int cg = w * 32;                        // this wave's 32 B-rows

    // ---- A panel to registers (rows chunk*16+fr and 128+chunk*16+fr) ----
    const short* gA0 = base + (size_t)(chunk * 16 + fr) * D + 8 * kg;
    const short* gA1 = gA0 + (size_t)128 * D;
    bf16x8 a0r[16], a1r[16];
    #pragma unroll
    for (int s = 0; s < 16; s++) {
        a0r[s] = *(const bf16x8*)(gA0 + s * 32);
        a1r[s] = *(const bf16x8*)(gA1 + s * 32);
    }

    // ---- B staging helper: slice ks -> buffer bi (wave-private region) ----
    auto stageB = [&](int ks, int bi) {
        #pragma unroll
        for (int t = 0; t < 2; t++) {
            const int sl  = t * 64 + lane;        // 16B chunk slot in wave region
            const int row = sl >> 2;              // 0..31
            const int pp  = sl & 3;               // stored position
            const int gch = pp ^ (row & 3);       // pre-swizzled source chunk
            const short* src = base + (size_t)(cg + row) * D + ks * 32 + gch * 8;
            glds16(src, &smem[bi * BBUF + w * 2048 + t * 1024]);  // +lane*16 implicit
        }
    };

    f32x4 acc00 = {0.f,0.f,0.f,0.f}, acc01 = {0.f,0.f,0.f,0.f};
    f32x4 acc10 = {0.f,0.f,0.f,0.f}, acc11 = {0.f,0.f,0.f,0.f};

    // prologue: queue = [A(32), B0(2), B1(2)]; wait until only B1 pending
    stageB(0, 0);
    stageB(1, 1);
    asm volatile("s_waitcnt vmcnt(2)" ::: "memory");
    __builtin_amdgcn_sched_barrier(0);

    const int pb = (kg ^ (fr & 3)) * 16;          // swizzled read position (bytes)
    #pragma unroll
    for (int s = 0; s < 16; s++) {
        if (s < 14) stageB(s + 2, (s + 2) % 3);   // queue: B(s+1), B(s+2)
        const int bo = (s % 3) * BBUF + w * 2048;
        bf16x8 b0 = *(const bf16x8*)&smem[bo + fr * 64 + pb];
        bf16x8 b1 = *(const bf16x8*)&smem[bo + (16 + fr) * 64 + pb];
        acc00 = __builtin_amdgcn_mfma_f32_16x16x32_bf16(a0r[s], b0, acc00, 0, 0, 0);
        acc01 = __builtin_amdgcn_mfma_f32_16x16x32_bf16(a0r[s], b1, acc01, 0, 0, 0);
        acc10 = __builtin_amdgcn_mfma_f32_16x16x32_bf16(a1r[s], b0, acc10, 0, 0, 0);
        acc11 = __builtin_amdgcn_mfma_f32_16x16x32_bf16(a1r[s], b1, acc11, 0, 0, 0);
        if (s < 14)      { asm volatile("s_waitcnt vmcnt(2)" ::: "memory"); }
        else if (s == 14){ asm volatile("s_waitcnt vmcnt(0)" ::: "memory"); }
        __builtin_amdgcn_sched_barrier(0);
    }

    __syncthreads();   // B arena dead; P overlays it

    float* P   = (float*)smem;                    // 32 x PSTR f32 = 33280 B
    float* red = (float*)&smem[49152];

    // C/D layout (m89-verified): lane l, reg q -> row (l>>4)*4+q, col l&15
    {
        const int rw = kg * 4;
        const int cw = cg + fr;                   // b0 cols = cg+fr, b1 = +16
        #pragma unroll
        for (int q = 0; q < 4; q++) P[(rw + q) * PSTR + cw]            = acc00[q];
        #pragma unroll
        for (int q = 0; q < 4; q++) P[(rw + q) * PSTR + cw + 16]      = acc01[q];
        #pragma unroll
        for (int q = 0; q < 4; q++) P[(16 + rw + q) * PSTR + cw]      = acc10[q];
        #pragma unroll
        for (int q = 0; q < 4; q++) P[(16 + rw + q) * PSTR + cw + 16] = acc11[q];
    }
    __syncthreads();

    // ---- Loss phase: 4 rows per wave, wave-private (verified rounds 3-5) ----
    float wacc = 0.f;
    #pragma unroll
    for (int rr = 0; rr < 4; rr++) {
        const int r      = w * 4 + rr;
        const int pd_off = (r < 16) ? 0 : 128;
        const int pn_off = 128 - pd_off;
        float* prow = &P[r * PSTR];

        const float g0 = prow[pd_off + lane];
        const float g1 = prow[pd_off + lane + 64];
        float v0 = prow[pn_off + lane];
        float v1 = prow[pn_off + lane + 64];

        // bitonic sort ascending (2 elems/lane)
        #pragma unroll
        for (int kk = 2; kk <= 128; kk <<= 1) {
            if (kk == 128) {
                const float lo = fminf(v0, v1);
                const float hi = fmaxf(v0, v1);
                v0 = lo; v1 = hi;
            }
            #pragma unroll
            for (int j = (kk == 128 ? 32 : (kk >> 1)); j >= 1; j >>= 1) {
                const float p0 = __shfl_xor(v0, j, 64);
                const float p1 = __shfl_xor(v1, j, 64);
                const bool up0 = (lane & kk) == 0;
                const bool up1 = ((lane + 64) & kk) == 0;
                const bool lower = (lane & j) == 0;
                v0 = (up0 == lower) ? fminf(v0, p0) : fmaxf(v0, p0);
                v1 = (up1 == lower) ? fminf(v1, p1) : fmaxf(v1, p1);
            }
        }

        // inclusive prefix scans of the two halves
        float inc0 = v0, inc1 = v1;
        #pragma unroll
        for (int o = 1; o < 64; o <<= 1) {
            const float t0 = __shfl_up(inc0, o, 64);
            const float t1 = __shfl_up(inc1, o, 64);
            if (lane >= o) { inc0 += t0; inc1 += t1; }
        }
        const float tot0  = __shfl(inc0, 63, 64);
        const float total = tot0 + __shfl(inc1, 63, 64);

        // write sorted s[0:128] and exclusive prefix pre[0:129]
        prow[lane]            = v0;
        prow[64 + lane]       = v1;
        prow[130 + 1 + lane]  = inc0;
        prow[130 + 65 + lane] = tot0 + inc1;
        if (lane == 0) prow[130] = 0.f;

        // per-j: rank via guarded binary search, closed-form num/den
        #pragma unroll
        for (int h = 0; h < 2; h++) {
            const float g   = h ? g1 : g0;
            const float tau = g - 0.5f * ALPHA;
            const float a   = ALPHA - 2.f * g;
            int pos = 0;
            #pragma unroll
            for (int st = 128; st > 0; st >>= 1) {
                const int nidx = pos + st;
                const float sv = prow[nidx - 1];
                pos = ((nidx <= 128) && (sv <= tau)) ? nidx : pos;
            }
            const float cnt = (float)(128 - pos);
            const float pre = prow[130 + pos];
            const float num = cnt * a + 2.f * (total - pre);
            wacc += num / (cnt + EPS);
        }
    }

    #pragma unroll
    for (int o = 32; o > 0; o >>= 1) wacc += __shfl_xor(wacc, o, 64);
    if (lane == 0) red[w] = wacc;
    __syncthreads();
    if (threadIdx.x == 0) {
        float s = 0.f;
        #pragma unroll
        for (int i = 0; i < 8; i++) s += red[i];
        part[p] = s;
    }
}

// ---------------------------------------------------------------------------
// K3: final reduction of 256 partials -> scalar loss.
__global__ __launch_bounds__(256) void k_reduce(const float* __restrict__ part,
                                                float* __restrict__ out) {
    __shared__ float red[4];
    const int wid  = threadIdx.x >> 6;
    const int lane = threadIdx.x & 63;
    float s = part[threadIdx.x];
    #pragma unroll
    for (int o = 32; o > 0; o >>= 1) s += __shfl_xor(s, o, 64);
    if (lane == 0) red[wid] = s;
    __syncthreads();
    if (threadIdx.x == 0) out[0] = (red[0] + red[1] + red[2] + red[3]) * INV_CNT;
}

// ---------------------------------------------------------------------------
extern "C" void kernel_launch(void* const* d_in, const int* in_sizes, int n_in,
                              void* d_out, int out_size, void* d_ws, size_t ws_size,
                              hipStream_t stream) {
    const float* latent = (const float*)d_in[0];
    float* out = (float*)d_out;
    char* wsb = (char*)d_ws;
    short* nrm  = (short*)(wsb + NORM_OFF);
    float* part = (float*)(wsb + PART_OFF);

    hipLaunchKernelGGL(k_normalize, dim3(2048), dim3(256), 0, stream, latent, nrm);
    hipLaunchKernelGGL(k_fused,     dim3(256),  dim3(512), 0, stream, nrm, part);
    hipLaunchKernelGGL(k_reduce,    dim3(1),    dim3(256), 0, stream, part, out);
}